// Round 10
// baseline (584.560 us; speedup 1.0000x reference)
//
#include <hip/hip_runtime.h>

// Problem constants (from the reference): D=15, C=2^15, P=2^15-1, M=4
// K = M*D = 60 path steps per sample, IN_DIM=1024, BATCH=32.
#define K_PATH 60
#define IN_DIM 1024
#define BATCH  32

// One 256-thread block per (sample, path-step) task. Each thread loads one
// float4 of x[b,:] and one float4 of W[row,:] (256 threads x 4 floats = 1024),
// FMA, 64-lane shuffle reduce, 4 wave partials through LDS, thread 0 writes:
//   out[task]              = dot(x[b,:], W[row,:]) + bias[row]
//   out[B*K + task]        = comb_labels[target[b]*K + k]
// Minimal dependency chain: one global load round per task.
__global__ __launch_bounds__(256) void hse_block_dot_kernel(
    const float* __restrict__ x,
    const float* __restrict__ W,
    const float* __restrict__ bias,
    const int*   __restrict__ comb_idx,
    const float* __restrict__ comb_labels,
    const int*   __restrict__ target,
    float*       __restrict__ out)
{
    const int task = blockIdx.x;           // 0 .. BATCH*K_PATH-1
    const int tid  = threadIdx.x;          // 0 .. 255
    const int b = task / K_PATH;
    const int k = task - b * K_PATH;
    const int t = target[b];
    const int row = comb_idx[t * K_PATH + k];

    const float4 xv = ((const float4*)(x + (size_t)b   * IN_DIM))[tid];
    const float4 wv = ((const float4*)(W + (size_t)row * IN_DIM))[tid];

    float acc;
    acc = xv.x * wv.x;
    acc = fmaf(xv.y, wv.y, acc);
    acc = fmaf(xv.z, wv.z, acc);
    acc = fmaf(xv.w, wv.w, acc);

    // 64-lane wave reduction
#pragma unroll
    for (int off = 32; off > 0; off >>= 1)
        acc += __shfl_down(acc, off, 64);

    __shared__ float part[4];
    if ((tid & 63) == 0) part[tid >> 6] = acc;
    __syncthreads();

    if (tid == 0) {
        float s = part[0] + part[1] + part[2] + part[3];
        out[task] = s + bias[row];
        out[BATCH * K_PATH + task] = comb_labels[t * K_PATH + k];
    }
}

extern "C" void kernel_launch(void* const* d_in, const int* in_sizes, int n_in,
                              void* d_out, int out_size, void* d_ws, size_t ws_size,
                              hipStream_t stream) {
    // setup_inputs() order: x, W, b, comb_idx, comb_labels, target
    const float* x           = (const float*)d_in[0];
    const float* W           = (const float*)d_in[1];
    const float* bias        = (const float*)d_in[2];
    const int*   comb_idx    = (const int*)d_in[3];
    const float* comb_labels = (const float*)d_in[4];
    const int*   target      = (const int*)d_in[5];
    float* out = (float*)d_out;

    const int tasks = BATCH * K_PATH;      // 1920 blocks, one per task
    hse_block_dot_kernel<<<tasks, 256, 0, stream>>>(
        x, W, bias, comb_idx, comb_labels, target, out);
}